// Round 2
// baseline (113194.836 us; speedup 1.0000x reference)
//
#include <hip/hip_runtime.h>
#include <hip/hip_bf16.h>

typedef __hip_bfloat16 bf16;

#define B_   256
#define T1_  128
#define S_   128
#define A_   32
#define H_   1024
#define E_   1024
#define MIN_STD 0.1f

// ---- dtype-flexible load/store: isbf resolved at runtime from device probe ----
__device__ __forceinline__ float loadT(const void* p, int isbf, long idx) {
  return isbf ? __bfloat162float(((const bf16*)p)[idx]) : ((const float*)p)[idx];
}
__device__ __forceinline__ void storeT(void* p, int isbf, long idx, float v) {
  if (isbf) ((bf16*)p)[idx] = __float2bfloat16(v);
  else      ((float*)p)[idx] = v;
}

// Probe: read nelem elements of a weight tensor (values ~N(0, 1/32)) AS bf16.
// True bf16 data -> all |v| tiny. f32 data read as bf16 -> even elements are
// float mantissa halves (uniform bits -> huge exponents / NaN). flag=1 => bf16.
__global__ void dtype_probe(const void* __restrict__ p, int nelem, int* __restrict__ flag) {
  __shared__ int bad;
  if (threadIdx.x == 0) bad = 0;
  __syncthreads();
  const bf16* q = (const bf16*)p;
  int lbad = 0;
  for (int i = threadIdx.x; i < nelem; i += 256) {
    float v = __bfloat162float(q[i]);
    if (!(fabsf(v) <= 1e6f)) lbad = 1;   // catches huge AND NaN
  }
  if (lbad) atomicOr(&bad, 1);
  __syncthreads();
  if (threadIdx.x == 0) *flag = bad ? 0 : 1;
}

// Generic TN GEMM: C[m][n] = act( sum_k A[m][k] * W[n][k] + bias[n] ), fp32 out.
// A operand split at K1 between A1 (k<K1) and A2 (k>=K1) to fuse the concats.
// a1m/a2m: 0 = buffer is always fp32 (ws intermediate), 1 = input dtype (flag).
// Tiles BM=BN=64, BK=32; 256 threads, 4x4 per thread, fp32 accumulate.
__global__ __launch_bounds__(256)
void gemm_tn(const void* __restrict__ A1, int a1m, int lda1,
             const void* __restrict__ A2, int a2m, int lda2, long aoff2, int K1,
             const void* __restrict__ W, int ldw,
             const void* __restrict__ bias,
             float* __restrict__ C, int ldc, int relu,
             int N, int K, const int* __restrict__ flagp)
{
  const int F  = *flagp;
  const int f1 = a1m & F;
  const int f2 = a2m & F;
  __shared__ float As[32][65];
  __shared__ float Ws[32][65];
  const int tid = threadIdx.x;
  const int m0 = blockIdx.y * 64;
  const int n0 = blockIdx.x * 64;
  const int ty = tid >> 4, tx = tid & 15;
  const int lr = tid >> 2;          // 0..63  row within tile
  const int lk = (tid & 3) * 8;     // 0,8,16,24 k offset
  float acc[4][4] = {};

  for (int kt = 0; kt < K; kt += 32) {
    #pragma unroll
    for (int j = 0; j < 8; ++j) {
      int kk = kt + lk + j;
      float v;
      if (kk < K1) v = loadT(A1, f1, (long)(m0 + lr) * lda1 + kk);
      else         v = loadT(A2, f2, (long)(m0 + lr) * lda2 + (kk - K1) + aoff2);
      As[lk + j][lr] = v;
    }
    #pragma unroll
    for (int j = 0; j < 8; ++j) {
      int kk = kt + lk + j;
      Ws[lk + j][lr] = loadT(W, F, (long)(n0 + lr) * ldw + kk);
    }
    __syncthreads();
    #pragma unroll
    for (int kk = 0; kk < 32; ++kk) {
      float ra[4], rw[4];
      #pragma unroll
      for (int i = 0; i < 4; ++i) ra[i] = As[kk][ty * 4 + i];
      #pragma unroll
      for (int j = 0; j < 4; ++j) rw[j] = Ws[kk][tx * 4 + j];
      #pragma unroll
      for (int i = 0; i < 4; ++i)
        #pragma unroll
        for (int j = 0; j < 4; ++j)
          acc[i][j] = fmaf(ra[i], rw[j], acc[i][j]);
    }
    __syncthreads();
  }

  #pragma unroll
  for (int j = 0; j < 4; ++j) {
    int n = n0 + tx * 4 + j;
    float bv = loadT(bias, F, n);
    #pragma unroll
    for (int i = 0; i < 4; ++i) {
      int m = m0 + ty * 4 + i;
      float v = acc[i][j] + bv;
      if (relu) v = fmaxf(v, 0.f);
      C[(long)m * ldc + n] = v;
    }
  }
}

// GRU elementwise: reads gi, gh (fp32), h_prev; writes b1 to output (flag dtype)
// and to fp32 carry. One thread per (b, j).
__global__ __launch_bounds__(256)
void gru_ew(const float* __restrict__ gi, const float* __restrict__ gh,
            const void* __restrict__ hprev, int hm, int ldh,
            void* __restrict__ out, int t, float* __restrict__ b_f,
            const int* __restrict__ flagp)
{
  const int F  = *flagp;
  const int fh = hm & F;
  int tid = blockIdx.x * 256 + threadIdx.x;   // 0 .. B*H-1
  int b = tid >> 10;
  int j = tid & 1023;
  long gbase = (long)b * 3072;
  float ir  = gi[gbase + j],         hr = gh[gbase + j];
  float iz  = gi[gbase + 1024 + j],  hz = gh[gbase + 1024 + j];
  float in_ = gi[gbase + 2048 + j],  hn = gh[gbase + 2048 + j];
  float h = loadT(hprev, fh, (long)b * ldh + j);
  float r = 1.f / (1.f + expf(-(ir + hr)));
  float z = 1.f / (1.f + expf(-(iz + hz)));
  float n = tanhf(in_ + r * hn);
  float v = (1.f - z) * n + z * h;
  storeT(out, F, (long)b * (T1_ * H_) + (long)t * H_ + j, v);
  b_f[(long)b * H_ + j] = v;
}

__device__ __forceinline__ float softplusf_(float x) {
  return fmaxf(x, 0.f) + log1pf(expf(-fabsf(x)));
}

// Sampling / head epilogue: one thread per (b, s).
__global__ __launch_bounds__(256)
void sample_ew(const float* __restrict__ catp, const float* __restrict__ catq,
               const void* __restrict__ npri, const void* __restrict__ npos,
               void* __restrict__ out, int t, float* __restrict__ s_f,
               const int* __restrict__ flagp)
{
  const int F = *flagp;
  int tid = blockIdx.x * 256 + threadIdx.x;   // 0 .. B*S-1
  int b = tid >> 7;
  int s = tid & 127;
  const long SZH = (long)B_ * T1_ * H_;       // y0 size
  const long SZS = (long)B_ * T1_ * S_;       // each small output size
  long nidx = (long)b * (T1_ * S_) + (long)t * S_ + s;
  long crow = (long)b * 256;
  float mu_p = catp[crow + s];
  float h2p  = catp[crow + 128 + s];
  float mu_q = catq[crow + s];
  float h2q  = catq[crow + 128 + s];
  float std_p = softplusf_(h2p) + MIN_STD;
  float std_q = softplusf_(h2q) + MIN_STD;
  float epv = loadT(npri, F, nidx);
  float eqv = loadT(npos, F, nidx);
  float s_p = mu_p + std_p * epv;
  float s_q = mu_q + std_q * eqv;
  storeT(out, F, SZH + 0 * SZS + nidx, s_p);
  storeT(out, F, SZH + 1 * SZS + nidx, mu_p);
  storeT(out, F, SZH + 2 * SZS + nidx, std_p);
  storeT(out, F, SZH + 3 * SZS + nidx, s_q);
  storeT(out, F, SZH + 4 * SZS + nidx, mu_q);
  storeT(out, F, SZH + 5 * SZS + nidx, std_q);
  s_f[(long)b * S_ + s] = s_q;
}

extern "C" void kernel_launch(void* const* d_in, const int* in_sizes, int n_in,
                              void* d_out, int out_size, void* d_ws, size_t ws_size,
                              hipStream_t stream) {
  const void* s0     = d_in[0];
  const void* b0     = d_in[1];
  const void* Act    = d_in[2];
  const void* Obs    = d_in[3];
  const void* npri   = d_in[4];
  const void* npos   = d_in[5];
  const void* W_sa   = d_in[6];
  const void* b_sa   = d_in[7];
  const void* W_ih   = d_in[8];
  const void* W_hh   = d_in[9];
  const void* b_ih   = d_in[10];
  const void* b_hh   = d_in[11];
  const void* W_bpri = d_in[12];
  const void* b_bpri = d_in[13];
  const void* W_spri = d_in[14];
  const void* b_spri = d_in[15];
  const void* W_bpos = d_in[16];
  const void* b_bpos = d_in[17];
  const void* W_spos = d_in[18];
  const void* b_spos = d_in[19];

  float* ws = (float*)d_ws;
  float* x_f    = ws;                    // B*H      = 262144
  float* gh_f   = x_f    + 262144;       // B*3H     = 786432
  float* gi_f   = gh_f   + 786432;       // B*3H     = 786432
  float* hp_f   = gi_f   + 786432;       // B*H      = 262144
  float* hq_f   = hp_f   + 262144;       // B*H      = 262144
  float* catp_f = hq_f   + 262144;       // B*2S     = 65536
  float* catq_f = catp_f + 65536;        // B*2S     = 65536
  float* b_f    = catq_f + 65536;        // B*H      = 262144
  float* s_f    = b_f    + 262144;       // B*S      = 32768
  int*   flagp  = (int*)(s_f + 32768);   // 1 int, ~10.6 MB into ws

  dim3 blk(256);

  // Resolve input dtype once per call (deterministic, graph-safe).
  dtype_probe<<<dim3(1), blk, 0, stream>>>(W_ih, 8192, flagp);

  for (int t = 0; t < T1_; ++t) {
    const void* sprev = t ? (const void*)s_f : s0;
    int sm = t ? 0 : 1;
    const void* bprev = t ? (const void*)b_f : b0;
    int bm = t ? 0 : 1;

    // x = relu([s,a] @ W_sa^T + b_sa)           M=256 N=1024 K=160 (128|32)
    gemm_tn<<<dim3(16, 4), blk, 0, stream>>>(
        sprev, sm, S_, Act, 1, T1_ * A_, (long)t * A_, S_,
        W_sa, S_ + A_, b_sa, x_f, H_, 1, H_, S_ + A_, flagp);

    // gh = h @ W_hh^T + b_hh                    M=256 N=3072 K=1024
    gemm_tn<<<dim3(48, 4), blk, 0, stream>>>(
        bprev, bm, H_, bprev, bm, H_, 0, H_,
        W_hh, H_, b_hh, gh_f, 3 * H_, 0, 3 * H_, H_, flagp);

    // gi = x @ W_ih^T + b_ih                    M=256 N=3072 K=1024
    gemm_tn<<<dim3(48, 4), blk, 0, stream>>>(
        x_f, 0, H_, x_f, 0, H_, 0, H_,
        W_ih, H_, b_ih, gi_f, 3 * H_, 0, 3 * H_, H_, flagp);

    // GRU elementwise -> b1 (output y0[:,t,:] and fp32 carry b_f)
    gru_ew<<<dim3(B_ * H_ / 256), blk, 0, stream>>>(
        gi_f, gh_f, bprev, bm, H_, d_out, t, b_f, flagp);

    // hp = relu(b1 @ W_bpri^T + b_bpri)         M=256 N=1024 K=1024
    gemm_tn<<<dim3(16, 4), blk, 0, stream>>>(
        b_f, 0, H_, b_f, 0, H_, 0, H_,
        W_bpri, H_, b_bpri, hp_f, H_, 1, H_, H_, flagp);

    // hq = relu([b1,o] @ W_bpos^T + b_bpos)     M=256 N=1024 K=2048 (1024|1024)
    gemm_tn<<<dim3(16, 4), blk, 0, stream>>>(
        b_f, 0, H_, Obs, 1, T1_ * E_, (long)t * E_, H_,
        W_bpos, H_ + E_, b_bpos, hq_f, H_, 1, H_, H_ + E_, flagp);

    // cat_p = hp @ W_spri^T + b_spri            M=256 N=256 K=1024
    gemm_tn<<<dim3(4, 4), blk, 0, stream>>>(
        hp_f, 0, H_, hp_f, 0, H_, 0, H_,
        W_spri, H_, b_spri, catp_f, 2 * S_, 0, 2 * S_, H_, flagp);

    // cat_q = hq @ W_spos^T + b_spos            M=256 N=256 K=1024
    gemm_tn<<<dim3(4, 4), blk, 0, stream>>>(
        hq_f, 0, H_, hq_f, 0, H_, 0, H_,
        W_spos, H_, b_spos, catq_f, 2 * S_, 0, 2 * S_, H_, flagp);

    // sampling epilogue -> y1..y6 and fp32 carry s_f
    sample_ew<<<dim3(B_ * S_ / 256), blk, 0, stream>>>(
        catp_f, catq_f, npri, npos, d_out, t, s_f, flagp);
  }
}